// Round 12
// baseline (210.823 us; speedup 1.0000x reference)
//
#include <hip/hip_runtime.h>

typedef unsigned short u16;
typedef __bf16 bf16x8 __attribute__((ext_vector_type(8)));   // gfx950 MFMA A/B fragment
typedef float f32x4 __attribute__((ext_vector_type(4)));
typedef float f32x2 __attribute__((ext_vector_type(2)));
typedef __bf16 bf16x2 __attribute__((ext_vector_type(2)));

__device__ __forceinline__ float b2f(u16 u) {
    unsigned int x = ((unsigned int)u) << 16;
    float f; __builtin_memcpy(&f, &x, 4); return f;
}
// HW bf16 convert (v_cvt_pk_bf16_f32, RTNE — bit-identical to manual round-to-nearest-even)
__device__ __forceinline__ u16 f2b(float f) {
    __bf16 h = (__bf16)f; u16 r; __builtin_memcpy(&r, &h, 2); return r;
}
__device__ __forceinline__ unsigned int pk2(float a, float b) {
    f32x2 v = {a, b};
    bf16x2 h = __builtin_convertvector(v, bf16x2);
    unsigned int r; __builtin_memcpy(&r, &h, 4); return r;
}

// ---------------------------------------------------------------------------
// k_prep (merged with transpose): fp32 weights -> bf16 fragment tilings, plus
// x NCHW -> x_t padded NHWC (blocks 2176..2431).  256 threads/block.
// ---------------------------------------------------------------------------
__global__ void k_prep(const float* __restrict__ w_om, const float* __restrict__ b_om,
                       const float* __restrict__ w_in, const float* __restrict__ w_dc,
                       const float* __restrict__ b_dc, const float* __restrict__ x,
                       u16* __restrict__ wv_om3, float* __restrict__ bv_om,
                       u16* __restrict__ wv_in2, u16* __restrict__ wv_dc2,
                       float* __restrict__ bv_dc, u16* __restrict__ x_t)
{
    __shared__ u16 sm[64 * 136];
    int blk = blockIdx.x, t = threadIdx.x;
    if (blk < 2048) {
        int m = blk, c = m >> 5, q = m & 31, g = m >> 7, ml = m & 127;
        bool pad = q >= 27;
        int src = 0;
        if (!pad) { int j = q / 9, k = q - j * 9; src = (j < 2) ? ((c * 9 + k) * 2 + j) : (1152 + c * 9 + k); }
        for (int idx = t; idx < 576; idx += 256) {
            int tap = idx >> 6, ci = idx & 63;
            int run = ci >> 3, j = ci & 7;
            u16 v = pad ? (u16)0 : f2b(w_om[(size_t)src * 576 + ci * 9 + tap]);
            wv_om3[(((size_t)g * 9 + tap) * 8 + run) * 1024 + ml * 8 + j] = v;
        }
        if (t == 0) bv_om[m] = pad ? 0.f : b_om[src];
    } else if (blk < 2112) {
        int m = blk - 2048;
        for (int idx = t; idx < 576; idx += 256) {
            int tap = idx >> 6, ci = idx & 63;
            int run = ci >> 3, j = ci & 7;
            wv_in2[(((size_t)tap * 8 + run) * 64 + m) * 8 + j] = f2b(w_in[(size_t)m * 576 + ci * 9 + tap]);
        }
    } else if (blk < 2176) {
        int m = blk - 2112;
        for (int idx = t; idx < 576; idx += 256)
            wv_dc2[((size_t)(idx >> 3) * 64 + m) * 8 + (idx & 7)] = f2b(w_dc[(size_t)m * 576 + idx]);
        if (t == 0) bv_dc[m] = b_dc[m];
    } else {
        int row = blk - 2176;
        int b = row >> 7, y = row & 127;
        for (int it = 0; it < 4; ++it) {
            int chunk = it * 256 + t;
            int ci = chunk >> 4, part = chunk & 15;
            const float4* src = (const float4*)(x + (((size_t)(b * 64 + ci) * 128 + y) * 128) + part * 8);
            float4 v0 = src[0], v1 = src[1];
            unsigned int tp[4] = { pk2(v0.x, v0.y), pk2(v0.z, v0.w),
                                   pk2(v1.x, v1.y), pk2(v1.z, v1.w) };
            *(uint4*)(&sm[ci * 136 + part * 8]) = *(uint4*)tp;
        }
        __syncthreads();
        int xx = t >> 1, half = t & 1;
        u16 tmp[32];
#pragma unroll
        for (int cc = 0; cc < 32; ++cc) tmp[cc] = sm[(half * 32 + cc) * 136 + xx];
        u16* dst = x_t + (((size_t)(b * 130) + y + 1) * 130 + (xx + 1)) * 64 + half * 32;
#pragma unroll
        for (int j = 0; j < 4; ++j) ((uint4*)dst)[j] = ((uint4*)tmp)[j];
    }
}

// ---------------------------------------------------------------------------
// k_conv1: split x4, barrier-free K-loop (structure unchanged; pk2 epilogue).
// ---------------------------------------------------------------------------
__global__ __launch_bounds__(256) void k_conv1(
    const u16* __restrict__ wv_in2, const float* __restrict__ b_in,
    const u16* __restrict__ x_t, u16* __restrict__ feat_t, u16* __restrict__ feat_c)
{
    __shared__ char smem[13440];            // Bw 8*3*35*16; epi: f32 om[64][33]
    float* om = (float*)smem;
    int xh = blockIdx.x, row = blockIdx.y, b = row >> 7, y = row & 127;
    int px0 = xh * 32;
    int t = threadIdx.x, lane = t & 63, wv = t >> 6;
    int wm = wv >> 1, wn = wv & 1, lm = lane & 15, kg = lane >> 4;
    f32x4 acc[2][1] = {};
    const u16* fb = x_t + (size_t)b * 130 * 130 * 64;
    for (int id = t; id < 816; id += 256) {
        int r3 = id / 272, rem = id - r3 * 272;
        int pix = rem >> 3, r2 = rem & 7;
        uint4 v = *(const uint4*)(fb + ((size_t)(y + r3) * 130 + px0) * 64 + rem * 8);
        *(uint4*)(smem + (((r2 * 3 + r3) * 35 + pix) << 4)) = v;
    }
    const u16* ab = wv_in2;
    int arow = (wm * 32 + lm) * 8;
    bf16x8 af[3][2];
#pragma unroll
    for (int mt = 0; mt < 2; ++mt)
        af[0][mt] = *(const bf16x8*)(ab + (size_t)kg * 512 + arow + mt * 128);
#pragma unroll
    for (int mt = 0; mt < 2; ++mt)
        af[1][mt] = *(const bf16x8*)(ab + (size_t)(4 + kg) * 512 + arow + mt * 128);
    __syncthreads();
#pragma unroll
    for (int s = 0; s < 18; ++s) {
        if (s < 16) {
            int s2 = s + 2, tap2 = s2 >> 1, run2 = (s2 & 1) * 4 + kg;
#pragma unroll
            for (int mt = 0; mt < 2; ++mt)
                af[(s + 2) % 3][mt] = *(const bf16x8*)(ab + ((size_t)tap2 * 8 + run2) * 512 + arow + mt * 128);
        }
        int tap = s >> 1, run = (s & 1) * 4 + kg;
        int dy = tap / 3, dx = tap - dy * 3;
        bf16x8 bf = *(const bf16x8*)(smem + (((run * 3 + dy) * 35 + wn * 16 + lm + dx) << 4));
#pragma unroll
        for (int mt = 0; mt < 2; ++mt)
            acc[mt][0] = __builtin_amdgcn_mfma_f32_16x16x32_bf16(af[s % 3][mt], bf, acc[mt][0], 0, 0, 0);
    }
    __syncthreads();
#pragma unroll
    for (int mt = 0; mt < 2; ++mt)
#pragma unroll
        for (int i = 0; i < 4; ++i) {
            int m = wm * 32 + mt * 16 + kg * 4 + i;
            int n = wn * 16 + lm;
            float v = acc[mt][0][i] + b_in[m];
            v = v > 0.f ? v : 0.1f * v;
            om[m * 33 + n] = v;
        }
    __syncthreads();
    for (int it = 0; it < 8; ++it) {
        int item = it * 256 + t, ci = item >> 5, xx = item & 31;
        feat_c[(((size_t)(ci * 2 + b)) * 128 + y) * 128 + px0 + xx] = f2b(om[ci * 33 + xx]);
    }
    {
        int xx = t >> 3, oo = t & 7;
        unsigned int tw[4];
#pragma unroll
        for (int c2 = 0; c2 < 4; ++c2)
            tw[c2] = pk2(om[(oo * 8 + c2 * 2) * 33 + xx], om[(oo * 8 + c2 * 2 + 1) * 33 + xx]);
        u16* dst = feat_t + (((size_t)(b * 130) + y + 1) * 130 + (px0 + xx + 1)) * 64 + oo * 8;
        *(uint4*)dst = *(uint4*)tw;
    }
}

// ---------------------------------------------------------------------------
// k_conv2 (round 12): GEMM unchanged; epilogue uses HW bf16 converts (pk2),
// precomputed sampling bases, omb stride 114 u16 (57 dwords, odd), ft f32
// stride 140 (16B-aligned rows).  LDS = 40,384 B.
// ---------------------------------------------------------------------------
__global__ __launch_bounds__(256) void k_conv2(
    const u16* __restrict__ wv_om3, const float* __restrict__ bv_om,
    const u16* __restrict__ feat_t, const u16* __restrict__ feat_c,
    u16* __restrict__ mod_t)
{
    __shared__ char smem[40384];            // Bw 34,048 | epi: omb 29,184 + ft(f32) 11,200
    u16* omb  = (u16*)smem;                 // col-major [pix][114]
    u16* modl = (u16*)smem;                 // overlays omb after B5
    float* ftf = (float*)(smem + 29184);    // [cl][r][140]
    int g = blockIdx.x, row = blockIdx.y;
    int b = row >> 7, y = row & 127;
    int t = threadIdx.x, lane = t & 63, wv = t >> 6;
    int wm = wv >> 1, wn = wv & 1, lm = lane & 15, kg = lane >> 4;
    f32x4 acc[4][4] = {};
    const u16* fb = feat_t + (size_t)b * 130 * 130 * 64;
    for (int id = t; id < 2080; id += 256) {           // rows y,y+1 -> slots 0,1
        int ds = id / 1040, rem = id - ds * 1040;
        int pix = rem >> 3, r2 = rem & 7;
        uint4 v = *(const uint4*)(fb + ((size_t)(y + ds) * 130) * 64 + rem * 8);
        *(uint4*)(smem + (((ds * 8 + r2) * 133 + pix) << 4)) = v;
    }
    const u16* ab = wv_om3 + (size_t)g * 9 * 8192;
    int arow = (wm * 64 + lm) * 8;
    bf16x8 af[3][4];
#pragma unroll
    for (int mt = 0; mt < 4; ++mt)
        af[0][mt] = *(const bf16x8*)(ab + (size_t)kg * 1024 + arow + mt * 128);
#pragma unroll
    for (int mt = 0; mt < 4; ++mt)
        af[1][mt] = *(const bf16x8*)(ab + (size_t)(4 + kg) * 1024 + arow + mt * 128);
    __syncthreads();                                   // B0
#pragma unroll
    for (int s = 0; s < 6; ++s) {                      // phase 0: dy0, slot0
        int s2 = s + 2, tap2 = s2 >> 1, run2 = (s2 & 1) * 4 + kg;
#pragma unroll
        for (int mt = 0; mt < 4; ++mt)
            af[s2 % 3][mt] = *(const bf16x8*)(ab + ((size_t)tap2 * 8 + run2) * 1024 + arow + mt * 128);
        int tap = s >> 1, run = (s & 1) * 4 + kg, dx = tap;
        bf16x8 bf[4];
#pragma unroll
        for (int nt = 0; nt < 4; ++nt)
            bf[nt] = *(const bf16x8*)(smem + ((run * 133 + wn * 64 + nt * 16 + lm + dx) << 4));
#pragma unroll
        for (int mt = 0; mt < 4; ++mt)
#pragma unroll
            for (int nt = 0; nt < 4; ++nt)
                acc[mt][nt] = __builtin_amdgcn_mfma_f32_16x16x32_bf16(af[s % 3][mt], bf[nt], acc[mt][nt], 0, 0, 0);
    }
    __syncthreads();                                   // B1
    uint4 r2v[5];
#pragma unroll
    for (int j = 0; j < 5; ++j) {
        int id = j * 256 + t;
        if (id < 1040) r2v[j] = *(const uint4*)(fb + ((size_t)(y + 2) * 130) * 64 + id * 8);
    }
#pragma unroll
    for (int s = 6; s < 12; ++s) {                     // phase 1: dy1, slot1
        int s2 = s + 2, tap2 = s2 >> 1, run2 = (s2 & 1) * 4 + kg;
#pragma unroll
        for (int mt = 0; mt < 4; ++mt)
            af[s2 % 3][mt] = *(const bf16x8*)(ab + ((size_t)tap2 * 8 + run2) * 1024 + arow + mt * 128);
        int tap = s >> 1, run = (s & 1) * 4 + kg, dx = tap - 3;
        bf16x8 bf[4];
#pragma unroll
        for (int nt = 0; nt < 4; ++nt)
            bf[nt] = *(const bf16x8*)(smem + (((8 + run) * 133 + wn * 64 + nt * 16 + lm + dx) << 4));
#pragma unroll
        for (int mt = 0; mt < 4; ++mt)
#pragma unroll
            for (int nt = 0; nt < 4; ++nt)
                acc[mt][nt] = __builtin_amdgcn_mfma_f32_16x16x32_bf16(af[s % 3][mt], bf[nt], acc[mt][nt], 0, 0, 0);
    }
#pragma unroll
    for (int j = 0; j < 5; ++j) {                      // row y+2 -> slot0
        int id = j * 256 + t;
        if (id < 1040) {
            int pix = id >> 3, r2 = id & 7;
            *(uint4*)(smem + ((r2 * 133 + pix) << 4)) = r2v[j];
        }
    }
    __syncthreads();                                   // B2 (slot1 dead -> ft region free)
    // ---- ft staging overlapped with phase 2 (bytes >= 29,184 only)
    if (t < 40) {                                      // zero halo cols 4..7 / 136..139
        int rr = t >> 1, side = t & 1;
        uint4 z = {0, 0, 0, 0};
        *(uint4*)(ftf + rr * 140 + (side ? 136 : 4)) = z;
    }
    for (int ch = t; ch < 320; ch += 256) {            // main fill, bf16 -> f32
        int cl = ch / 80, rem = ch - cl * 80;
        int r = rem >> 4, part = rem & 15;
        int gy = y + r - 2;
        float vf[8];
        if ((unsigned)gy < 128u) {
            uint4 v = *(const uint4*)(feat_c + ((size_t)((g * 4 + cl) * 2 + b)) * 16384 + gy * 128 + part * 8);
            const u16* vp = (const u16*)&v;
#pragma unroll
            for (int j = 0; j < 8; ++j) vf[j] = b2f(vp[j]);
        } else {
#pragma unroll
            for (int j = 0; j < 8; ++j) vf[j] = 0.f;
        }
        float* d = ftf + (cl * 5 + r) * 140 + 8 + part * 8;
        *(uint4*)d = *(uint4*)&vf[0];
        *(uint4*)(d + 4) = *(uint4*)&vf[4];
    }
#pragma unroll
    for (int s = 12; s < 18; ++s) {                    // phase 2: dy2, slot0=row y+2
        if (s < 16) {
            int s2 = s + 2, tap2 = s2 >> 1, run2 = (s2 & 1) * 4 + kg;
#pragma unroll
            for (int mt = 0; mt < 4; ++mt)
                af[s2 % 3][mt] = *(const bf16x8*)(ab + ((size_t)tap2 * 8 + run2) * 1024 + arow + mt * 128);
        }
        int tap = s >> 1, run = (s & 1) * 4 + kg, dx = tap - 6;
        bf16x8 bf[4];
#pragma unroll
        for (int nt = 0; nt < 4; ++nt)
            bf[nt] = *(const bf16x8*)(smem + ((run * 133 + wn * 64 + nt * 16 + lm + dx) << 4));
#pragma unroll
        for (int mt = 0; mt < 4; ++mt)
#pragma unroll
            for (int nt = 0; nt < 4; ++nt)
                acc[mt][nt] = __builtin_amdgcn_mfma_f32_16x16x32_bf16(af[s % 3][mt], bf[nt], acc[mt][nt], 0, 0, 0);
    }
    __syncthreads();                                   // B3 (Bw dead -> omb)
    // ---- dump om (bias + HW bf16 pk2) column-major, packed b32 pairs
#pragma unroll
    for (int mt = 0; mt < 4; ++mt) {
        int cl = wm * 2 + (mt >> 1);
        int q0 = (mt & 1) * 16 + kg * 4;
        if (q0 != 28) {
            float4 bs = *(const float4*)(bv_om + g * 128 + wm * 64 + mt * 16 + kg * 4);
#pragma unroll
            for (int nt = 0; nt < 4; ++nt) {
                int n = wn * 64 + nt * 16 + lm;
                unsigned int lo = pk2(acc[mt][nt][0] + bs.x, acc[mt][nt][1] + bs.y);
                unsigned int hi = pk2(acc[mt][nt][2] + bs.z, acc[mt][nt][3] + bs.w);
                unsigned int* p = (unsigned int*)(omb + n * 114 + cl * 28 + q0);
                p[0] = lo; p[1] = hi;
            }
        }
    }
    __syncthreads();                                   // B4
    // ---- sampling: precomputed bases, compile-time k, f32 ft
    int th = t >> 7, xx = t & 127;
    const u16* ob0 = omb + xx * 114 + th * 56;
    const float* ftb = ftf + th * 1400 + 7 + xx;       // cl base: th*2*700 ; +7+xx col base
    unsigned int sres[9];
#pragma unroll
    for (int j = 0; j < 9; ++j) {
        float sv[2];
#pragma unroll
        for (int h = 0; h < 2; ++h) {
            const int it = j * 2 + h;
            const int kk = it % 9, d9 = it / 9;        // compile-time
            const u16* ob = ob0 + d9 * 28;
            float offy = b2f(ob[kk]);
            float offx = b2f(ob[kk + 9]);
            float mv   = b2f(ob[kk + 18]);
            float msk = 1.f / (1.f + __expf(-mv));
            float fy = floorf(offy), fx = floorf(offx);
            float wy = offy - fy, wx = offx - fx;
            int ri = (int)fy, ci = (int)fx;
            const float* base = ftb + d9 * 700 + (kk / 3 + 1) * 140 + (kk % 3) + ri * 140 + ci;
            float v00 = base[0], v01 = base[1];
            float v10 = base[140], v11 = base[141];
            float h0 = v00 + wx * (v01 - v00);
            float h1 = v10 + wx * (v11 - v10);
            sv[h] = (h0 + wy * (h1 - h0)) * msk;
        }
        sres[j] = pk2(sv[0], sv[1]);
    }
    __syncthreads();                                   // B5 (omb reads done -> modl)
    {
        unsigned int* ml = (unsigned int*)modl;
        int base = xx * 19 + th * 9;
#pragma unroll
        for (int j = 0; j < 9; ++j) ml[base + j] = sres[j];
    }
    __syncthreads();                                   // B6
    {
        unsigned int* mo = (unsigned int*)mod_t;
        const unsigned int* ml = (const unsigned int*)modl;
        for (int w = t; w < 2304; w += 256) {
            int pix = w / 18, widx = w - pix * 18;
            mo[((size_t)(row * 128 + pix)) * 288 + g * 18 + widx] = ml[pix * 19 + widx];
        }
    }
}

// ---------------------------------------------------------------------------
// k_gemm3: grid (4, 256), 32-px tiles (unchanged from round 11).
// ---------------------------------------------------------------------------
__global__ __launch_bounds__(256) void k_gemm3(
    const u16* __restrict__ wv_dc2, const float* __restrict__ bv_dc,
    const u16* __restrict__ mod_t, float* __restrict__ out)
{
    __shared__ char smem[8192];             // 2 x 4KB B buffers
    int xh = blockIdx.x, row = blockIdx.y, b = row >> 7, y = row & 127;
    int t = threadIdx.x, lane = t & 63, wv = t >> 6;
    int wm = wv >> 1, wn = wv & 1, lm = lane & 15, kg = lane >> 4;
    f32x4 acc[2][1] = {};
    size_t p0 = (size_t)row * 128 + xh * 32;
    int pix = t >> 3, run = t & 7;
    int slot = (run << 5) + (pix ^ run);
    *(uint4*)(smem + slot * 16) = *(const uint4*)(mod_t + (p0 + pix) * 576 + run * 8);
    __syncthreads();
#pragma unroll
    for (int kc = 0; kc < 9; ++kc) {
        char* bb = smem + (kc & 1) * 4096;
        uint4 pre;
        if (kc < 8)
            pre = *(const uint4*)(mod_t + (p0 + pix) * 576 + (kc + 1) * 64 + run * 8);
#pragma unroll
        for (int ks = 0; ks < 2; ++ks) {
            int rn = ks * 4 + kg;
            bf16x8 af[2];
#pragma unroll
            for (int mt = 0; mt < 2; ++mt)
                af[mt] = *(const bf16x8*)(wv_dc2 + (((size_t)kc * 8 + rn) * 64 + wm * 32 + mt * 16 + lm) * 8);
            int n = wn * 16 + lm;
            bf16x8 bf = *(const bf16x8*)(bb + ((rn << 5) + (n ^ rn)) * 16);
#pragma unroll
            for (int mt = 0; mt < 2; ++mt)
                acc[mt][0] = __builtin_amdgcn_mfma_f32_16x16x32_bf16(af[mt], bf, acc[mt][0], 0, 0, 0);
        }
        if (kc < 8) {
            char* nb = smem + ((kc & 1) ^ 1) * 4096;
            *(uint4*)(nb + slot * 16) = pre;
        }
        __syncthreads();
    }
#pragma unroll
    for (int mt = 0; mt < 2; ++mt)
#pragma unroll
        for (int i = 0; i < 4; ++i) {
            int o = wm * 32 + mt * 16 + kg * 4 + i;
            int n = wn * 16 + lm;
            float v = acc[mt][0][i] + bv_dc[o];
            v = v > 0.f ? v : 0.f;
            out[(((size_t)(b * 64 + o)) * 128 + y) * 128 + xh * 32 + n] = v;
        }
}

// ---------------------------------------------------------------------------
// workspace layout: unchanged.
// ---------------------------------------------------------------------------
extern "C" void kernel_launch(void* const* d_in, const int* in_sizes, int n_in,
                              void* d_out, int out_size, void* d_ws, size_t ws_size,
                              hipStream_t stream)
{
    (void)in_sizes; (void)n_in; (void)out_size; (void)ws_size;
    const float* x    = (const float*)d_in[0];
    const float* w_in = (const float*)d_in[1];
    const float* b_in = (const float*)d_in[2];
    const float* w_om = (const float*)d_in[3];
    const float* b_om = (const float*)d_in[4];
    const float* w_dc = (const float*)d_in[5];
    const float* b_dc = (const float*)d_in[6];
    char* ws = (char*)d_ws;
    u16*   x_t    = (u16*)(ws);
    u16*   feat_t = (u16*)(ws + 4326400);
    u16*   feat_c = (u16*)(ws + 8652800);
    u16*   wv_om3 = (u16*)(ws + 12847104);
    u16*   wv_in2 = (u16*)(ws + 15206400);
    u16*   wv_dc2 = (u16*)(ws + 15280128);
    float* bv_om  = (float*)(ws + 15353856);
    float* bv_dc  = (float*)(ws + 15362048);
    u16*   mod_t  = (u16*)(ws + 15362304);

    hipMemsetAsync(ws, 0, 8652800, stream);   // zero x_t + feat_t (conv zero-padding)
    hipLaunchKernelGGL(k_prep, dim3(2432), dim3(256), 0, stream,
                       w_om, b_om, w_in, w_dc, b_dc, x,
                       wv_om3, bv_om, wv_in2, wv_dc2, bv_dc, x_t);
    hipLaunchKernelGGL(k_conv1, dim3(4, 256), dim3(256), 0, stream,
                       wv_in2, b_in, x_t, feat_t, feat_c);
    hipLaunchKernelGGL(k_conv2, dim3(16, 256), dim3(256), 0, stream,
                       wv_om3, bv_om, feat_t, feat_c, mod_t);
    hipLaunchKernelGGL(k_gemm3, dim3(4, 256), dim3(256), 0, stream,
                       wv_dc2, bv_dc, mod_t, (float*)d_out);
}

// Round 13
// 184.226 us; speedup vs baseline: 1.1444x; 1.1444x over previous
//
#include <hip/hip_runtime.h>

typedef unsigned short u16;
typedef __bf16 bf16x8 __attribute__((ext_vector_type(8)));   // gfx950 MFMA A/B fragment
typedef float f32x4 __attribute__((ext_vector_type(4)));
typedef float f32x2 __attribute__((ext_vector_type(2)));
typedef __bf16 bf16x2 __attribute__((ext_vector_type(2)));

__device__ __forceinline__ float b2f(u16 u) {
    unsigned int x = ((unsigned int)u) << 16;
    float f; __builtin_memcpy(&f, &x, 4); return f;
}
// HW bf16 convert (RTNE)
__device__ __forceinline__ u16 f2b(float f) {
    __bf16 h = (__bf16)f; u16 r; __builtin_memcpy(&r, &h, 2); return r;
}
__device__ __forceinline__ unsigned int pk2(float a, float b) {
    f32x2 v = {a, b};
    bf16x2 h = __builtin_convertvector(v, bf16x2);
    unsigned int r; __builtin_memcpy(&r, &h, 4); return r;
}

// ---------------------------------------------------------------------------
// k_prep (merged with transpose): unchanged from round 12.
// ---------------------------------------------------------------------------
__global__ void k_prep(const float* __restrict__ w_om, const float* __restrict__ b_om,
                       const float* __restrict__ w_in, const float* __restrict__ w_dc,
                       const float* __restrict__ b_dc, const float* __restrict__ x,
                       u16* __restrict__ wv_om3, float* __restrict__ bv_om,
                       u16* __restrict__ wv_in2, u16* __restrict__ wv_dc2,
                       float* __restrict__ bv_dc, u16* __restrict__ x_t)
{
    __shared__ u16 sm[64 * 136];
    int blk = blockIdx.x, t = threadIdx.x;
    if (blk < 2048) {
        int m = blk, c = m >> 5, q = m & 31, g = m >> 7, ml = m & 127;
        bool pad = q >= 27;
        int src = 0;
        if (!pad) { int j = q / 9, k = q - j * 9; src = (j < 2) ? ((c * 9 + k) * 2 + j) : (1152 + c * 9 + k); }
        for (int idx = t; idx < 576; idx += 256) {
            int tap = idx >> 6, ci = idx & 63;
            int run = ci >> 3, j = ci & 7;
            u16 v = pad ? (u16)0 : f2b(w_om[(size_t)src * 576 + ci * 9 + tap]);
            wv_om3[(((size_t)g * 9 + tap) * 8 + run) * 1024 + ml * 8 + j] = v;
        }
        if (t == 0) bv_om[m] = pad ? 0.f : b_om[src];
    } else if (blk < 2112) {
        int m = blk - 2048;
        for (int idx = t; idx < 576; idx += 256) {
            int tap = idx >> 6, ci = idx & 63;
            int run = ci >> 3, j = ci & 7;
            wv_in2[(((size_t)tap * 8 + run) * 64 + m) * 8 + j] = f2b(w_in[(size_t)m * 576 + ci * 9 + tap]);
        }
    } else if (blk < 2176) {
        int m = blk - 2112;
        for (int idx = t; idx < 576; idx += 256)
            wv_dc2[((size_t)(idx >> 3) * 64 + m) * 8 + (idx & 7)] = f2b(w_dc[(size_t)m * 576 + idx]);
        if (t == 0) bv_dc[m] = b_dc[m];
    } else {
        int row = blk - 2176;
        int b = row >> 7, y = row & 127;
        for (int it = 0; it < 4; ++it) {
            int chunk = it * 256 + t;
            int ci = chunk >> 4, part = chunk & 15;
            const float4* src = (const float4*)(x + (((size_t)(b * 64 + ci) * 128 + y) * 128) + part * 8);
            float4 v0 = src[0], v1 = src[1];
            unsigned int tp[4] = { pk2(v0.x, v0.y), pk2(v0.z, v0.w),
                                   pk2(v1.x, v1.y), pk2(v1.z, v1.w) };
            *(uint4*)(&sm[ci * 136 + part * 8]) = *(uint4*)tp;
        }
        __syncthreads();
        int xx = t >> 1, half = t & 1;
        u16 tmp[32];
#pragma unroll
        for (int cc = 0; cc < 32; ++cc) tmp[cc] = sm[(half * 32 + cc) * 136 + xx];
        u16* dst = x_t + (((size_t)(b * 130) + y + 1) * 130 + (xx + 1)) * 64 + half * 32;
#pragma unroll
        for (int j = 0; j < 4; ++j) ((uint4*)dst)[j] = ((uint4*)tmp)[j];
    }
}

// ---------------------------------------------------------------------------
// k_conv1: unchanged from round 12.
// ---------------------------------------------------------------------------
__global__ __launch_bounds__(256) void k_conv1(
    const u16* __restrict__ wv_in2, const float* __restrict__ b_in,
    const u16* __restrict__ x_t, u16* __restrict__ feat_t, u16* __restrict__ feat_c)
{
    __shared__ char smem[13440];
    float* om = (float*)smem;
    int xh = blockIdx.x, row = blockIdx.y, b = row >> 7, y = row & 127;
    int px0 = xh * 32;
    int t = threadIdx.x, lane = t & 63, wv = t >> 6;
    int wm = wv >> 1, wn = wv & 1, lm = lane & 15, kg = lane >> 4;
    f32x4 acc[2][1] = {};
    const u16* fb = x_t + (size_t)b * 130 * 130 * 64;
    for (int id = t; id < 816; id += 256) {
        int r3 = id / 272, rem = id - r3 * 272;
        int pix = rem >> 3, r2 = rem & 7;
        uint4 v = *(const uint4*)(fb + ((size_t)(y + r3) * 130 + px0) * 64 + rem * 8);
        *(uint4*)(smem + (((r2 * 3 + r3) * 35 + pix) << 4)) = v;
    }
    const u16* ab = wv_in2;
    int arow = (wm * 32 + lm) * 8;
    bf16x8 af[3][2];
#pragma unroll
    for (int mt = 0; mt < 2; ++mt)
        af[0][mt] = *(const bf16x8*)(ab + (size_t)kg * 512 + arow + mt * 128);
#pragma unroll
    for (int mt = 0; mt < 2; ++mt)
        af[1][mt] = *(const bf16x8*)(ab + (size_t)(4 + kg) * 512 + arow + mt * 128);
    __syncthreads();
#pragma unroll
    for (int s = 0; s < 18; ++s) {
        if (s < 16) {
            int s2 = s + 2, tap2 = s2 >> 1, run2 = (s2 & 1) * 4 + kg;
#pragma unroll
            for (int mt = 0; mt < 2; ++mt)
                af[(s + 2) % 3][mt] = *(const bf16x8*)(ab + ((size_t)tap2 * 8 + run2) * 512 + arow + mt * 128);
        }
        int tap = s >> 1, run = (s & 1) * 4 + kg;
        int dy = tap / 3, dx = tap - dy * 3;
        bf16x8 bf = *(const bf16x8*)(smem + (((run * 3 + dy) * 35 + wn * 16 + lm + dx) << 4));
#pragma unroll
        for (int mt = 0; mt < 2; ++mt)
            acc[mt][0] = __builtin_amdgcn_mfma_f32_16x16x32_bf16(af[s % 3][mt], bf, acc[mt][0], 0, 0, 0);
    }
    __syncthreads();
#pragma unroll
    for (int mt = 0; mt < 2; ++mt)
#pragma unroll
        for (int i = 0; i < 4; ++i) {
            int m = wm * 32 + mt * 16 + kg * 4 + i;
            int n = wn * 16 + lm;
            float v = acc[mt][0][i] + b_in[m];
            v = v > 0.f ? v : 0.1f * v;
            om[m * 33 + n] = v;
        }
    __syncthreads();
    for (int it = 0; it < 8; ++it) {
        int item = it * 256 + t, ci = item >> 5, xx = item & 31;
        feat_c[(((size_t)(ci * 2 + b)) * 128 + y) * 128 + px0 + xx] = f2b(om[ci * 33 + xx]);
    }
    {
        int xx = t >> 3, oo = t & 7;
        unsigned int tw[4];
#pragma unroll
        for (int c2 = 0; c2 < 4; ++c2)
            tw[c2] = pk2(om[(oo * 8 + c2 * 2) * 33 + xx], om[(oo * 8 + c2 * 2 + 1) * 33 + xx]);
        u16* dst = feat_t + (((size_t)(b * 130) + y + 1) * 130 + (px0 + xx + 1)) * 64 + oo * 8;
        *(uint4*)dst = *(uint4*)tw;
    }
}

// ---------------------------------------------------------------------------
// k_conv2 (round 13): register diet for 4 blocks/CU (128-reg cap).
//   - af[2][4] distance-1 prefetch (was [3][4]): -16 VGPR.
//   - row y+2 loaded AFTER phase 1 (no r2v held across it): -20 VGPR at peak.
//   - __launch_bounds__(256,4): 512/4 = 128 unified regs; 64 arch + 64 acc.
//   LDS 40,384 x 4 = 161.5KB <= 160KiB budget -> 4 blocks/CU.
// ---------------------------------------------------------------------------
__global__ __launch_bounds__(256, 4) void k_conv2(
    const u16* __restrict__ wv_om3, const float* __restrict__ bv_om,
    const u16* __restrict__ feat_t, const u16* __restrict__ feat_c,
    u16* __restrict__ mod_t)
{
    __shared__ char smem[40384];            // Bw 34,048 | epi: omb 29,184 + ft(f32) 11,200
    u16* omb  = (u16*)smem;                 // col-major [pix][114]
    u16* modl = (u16*)smem;                 // overlays omb after B5
    float* ftf = (float*)(smem + 29184);    // [cl][r][140]
    int g = blockIdx.x, row = blockIdx.y;
    int b = row >> 7, y = row & 127;
    int t = threadIdx.x, lane = t & 63, wv = t >> 6;
    int wm = wv >> 1, wn = wv & 1, lm = lane & 15, kg = lane >> 4;
    f32x4 acc[4][4] = {};
    const u16* fb = feat_t + (size_t)b * 130 * 130 * 64;
    for (int id = t; id < 2080; id += 256) {           // rows y,y+1 -> slots 0,1
        int ds = id / 1040, rem = id - ds * 1040;
        int pix = rem >> 3, r2 = rem & 7;
        uint4 v = *(const uint4*)(fb + ((size_t)(y + ds) * 130) * 64 + rem * 8);
        *(uint4*)(smem + (((ds * 8 + r2) * 133 + pix) << 4)) = v;
    }
    const u16* ab = wv_om3 + (size_t)g * 9 * 8192;
    int arow = (wm * 64 + lm) * 8;
    bf16x8 af[2][4];
#pragma unroll
    for (int mt = 0; mt < 4; ++mt)                     // s=0: tap0, run=kg
        af[0][mt] = *(const bf16x8*)(ab + (size_t)kg * 1024 + arow + mt * 128);
    __syncthreads();                                   // B0
#pragma unroll
    for (int s = 0; s < 6; ++s) {                      // phase 0: dy0, slot0
        int s1 = s + 1, tap1 = s1 >> 1, run1 = (s1 & 1) * 4 + kg;
#pragma unroll
        for (int mt = 0; mt < 4; ++mt)
            af[s1 & 1][mt] = *(const bf16x8*)(ab + ((size_t)tap1 * 8 + run1) * 1024 + arow + mt * 128);
        int tap = s >> 1, run = (s & 1) * 4 + kg, dx = tap;
        bf16x8 bf[4];
#pragma unroll
        for (int nt = 0; nt < 4; ++nt)
            bf[nt] = *(const bf16x8*)(smem + ((run * 133 + wn * 64 + nt * 16 + lm + dx) << 4));
#pragma unroll
        for (int mt = 0; mt < 4; ++mt)
#pragma unroll
            for (int nt = 0; nt < 4; ++nt)
                acc[mt][nt] = __builtin_amdgcn_mfma_f32_16x16x32_bf16(af[s & 1][mt], bf[nt], acc[mt][nt], 0, 0, 0);
    }
    __syncthreads();                                   // B1
#pragma unroll
    for (int s = 6; s < 12; ++s) {                     // phase 1: dy1, slot1
        int s1 = s + 1, tap1 = s1 >> 1, run1 = (s1 & 1) * 4 + kg;
#pragma unroll
        for (int mt = 0; mt < 4; ++mt)
            af[s1 & 1][mt] = *(const bf16x8*)(ab + ((size_t)tap1 * 8 + run1) * 1024 + arow + mt * 128);
        int tap = s >> 1, run = (s & 1) * 4 + kg, dx = tap - 3;
        bf16x8 bf[4];
#pragma unroll
        for (int nt = 0; nt < 4; ++nt)
            bf[nt] = *(const bf16x8*)(smem + (((8 + run) * 133 + wn * 64 + nt * 16 + lm + dx) << 4));
#pragma unroll
        for (int mt = 0; mt < 4; ++mt)
#pragma unroll
            for (int nt = 0; nt < 4; ++nt)
                acc[mt][nt] = __builtin_amdgcn_mfma_f32_16x16x32_bf16(af[s & 1][mt], bf[nt], acc[mt][nt], 0, 0, 0);
    }
    // ---- row y+2 -> slot0 (loaded here, not held across phase 1)
    for (int id = t; id < 1040; id += 256) {
        uint4 v = *(const uint4*)(fb + ((size_t)(y + 2) * 130) * 64 + id * 8);
        int pix = id >> 3, r2 = id & 7;
        *(uint4*)(smem + ((r2 * 133 + pix) << 4)) = v;
    }
    __syncthreads();                                   // B2 (slot1 dead -> ft region free)
    // ---- ft staging overlapped with phase 2 (bytes >= 29,184 only)
    if (t < 40) {                                      // zero halo cols 4..7 / 136..139
        int rr = t >> 1, side = t & 1;
        uint4 z = {0, 0, 0, 0};
        *(uint4*)(ftf + rr * 140 + (side ? 136 : 4)) = z;
    }
    for (int ch = t; ch < 320; ch += 256) {            // main fill, bf16 -> f32
        int cl = ch / 80, rem = ch - cl * 80;
        int r = rem >> 4, part = rem & 15;
        int gy = y + r - 2;
        float vf[8];
        if ((unsigned)gy < 128u) {
            uint4 v = *(const uint4*)(feat_c + ((size_t)((g * 4 + cl) * 2 + b)) * 16384 + gy * 128 + part * 8);
            const u16* vp = (const u16*)&v;
#pragma unroll
            for (int j = 0; j < 8; ++j) vf[j] = b2f(vp[j]);
        } else {
#pragma unroll
            for (int j = 0; j < 8; ++j) vf[j] = 0.f;
        }
        float* d = ftf + (cl * 5 + r) * 140 + 8 + part * 8;
        *(uint4*)d = *(uint4*)&vf[0];
        *(uint4*)(d + 4) = *(uint4*)&vf[4];
    }
#pragma unroll
    for (int s = 12; s < 18; ++s) {                    // phase 2: dy2, slot0=row y+2
        if (s < 17) {
            int s1 = s + 1, tap1 = s1 >> 1, run1 = (s1 & 1) * 4 + kg;
#pragma unroll
            for (int mt = 0; mt < 4; ++mt)
                af[s1 & 1][mt] = *(const bf16x8*)(ab + ((size_t)tap1 * 8 + run1) * 1024 + arow + mt * 128);
        }
        int tap = s >> 1, run = (s & 1) * 4 + kg, dx = tap - 6;
        bf16x8 bf[4];
#pragma unroll
        for (int nt = 0; nt < 4; ++nt)
            bf[nt] = *(const bf16x8*)(smem + ((run * 133 + wn * 64 + nt * 16 + lm + dx) << 4));
#pragma unroll
        for (int mt = 0; mt < 4; ++mt)
#pragma unroll
            for (int nt = 0; nt < 4; ++nt)
                acc[mt][nt] = __builtin_amdgcn_mfma_f32_16x16x32_bf16(af[s & 1][mt], bf[nt], acc[mt][nt], 0, 0, 0);
    }
    __syncthreads();                                   // B3 (Bw dead -> omb)
    // ---- dump om (bias + pk2) column-major, packed b32 pairs
#pragma unroll
    for (int mt = 0; mt < 4; ++mt) {
        int cl = wm * 2 + (mt >> 1);
        int q0 = (mt & 1) * 16 + kg * 4;
        if (q0 != 28) {
            float4 bs = *(const float4*)(bv_om + g * 128 + wm * 64 + mt * 16 + kg * 4);
#pragma unroll
            for (int nt = 0; nt < 4; ++nt) {
                int n = wn * 64 + nt * 16 + lm;
                unsigned int lo = pk2(acc[mt][nt][0] + bs.x, acc[mt][nt][1] + bs.y);
                unsigned int hi = pk2(acc[mt][nt][2] + bs.z, acc[mt][nt][3] + bs.w);
                unsigned int* p = (unsigned int*)(omb + n * 114 + cl * 28 + q0);
                p[0] = lo; p[1] = hi;
            }
        }
    }
    __syncthreads();                                   // B4
    // ---- sampling: precomputed bases, compile-time k, f32 ft
    int th = t >> 7, xx = t & 127;
    const u16* ob0 = omb + xx * 114 + th * 56;
    const float* ftb = ftf + th * 1400 + 7 + xx;
    unsigned int sres[9];
#pragma unroll
    for (int j = 0; j < 9; ++j) {
        float sv[2];
#pragma unroll
        for (int h = 0; h < 2; ++h) {
            const int it = j * 2 + h;
            const int kk = it % 9, d9 = it / 9;        // compile-time
            const u16* ob = ob0 + d9 * 28;
            float offy = b2f(ob[kk]);
            float offx = b2f(ob[kk + 9]);
            float mv   = b2f(ob[kk + 18]);
            float msk = 1.f / (1.f + __expf(-mv));
            float fy = floorf(offy), fx = floorf(offx);
            float wy = offy - fy, wx = offx - fx;
            int ri = (int)fy, ci = (int)fx;
            const float* base = ftb + d9 * 700 + (kk / 3 + 1) * 140 + (kk % 3) + ri * 140 + ci;
            float v00 = base[0], v01 = base[1];
            float v10 = base[140], v11 = base[141];
            float h0 = v00 + wx * (v01 - v00);
            float h1 = v10 + wx * (v11 - v10);
            sv[h] = (h0 + wy * (h1 - h0)) * msk;
        }
        sres[j] = pk2(sv[0], sv[1]);
    }
    __syncthreads();                                   // B5 (omb reads done -> modl)
    {
        unsigned int* ml = (unsigned int*)modl;
        int base = xx * 19 + th * 9;
#pragma unroll
        for (int j = 0; j < 9; ++j) ml[base + j] = sres[j];
    }
    __syncthreads();                                   // B6
    {
        unsigned int* mo = (unsigned int*)mod_t;
        const unsigned int* ml = (const unsigned int*)modl;
        for (int w = t; w < 2304; w += 256) {
            int pix = w / 18, widx = w - pix * 18;
            mo[((size_t)(row * 128 + pix)) * 288 + g * 18 + widx] = ml[pix * 19 + widx];
        }
    }
}

// ---------------------------------------------------------------------------
// k_gemm3: unchanged from round 11/12.
// ---------------------------------------------------------------------------
__global__ __launch_bounds__(256) void k_gemm3(
    const u16* __restrict__ wv_dc2, const float* __restrict__ bv_dc,
    const u16* __restrict__ mod_t, float* __restrict__ out)
{
    __shared__ char smem[8192];             // 2 x 4KB B buffers
    int xh = blockIdx.x, row = blockIdx.y, b = row >> 7, y = row & 127;
    int t = threadIdx.x, lane = t & 63, wv = t >> 6;
    int wm = wv >> 1, wn = wv & 1, lm = lane & 15, kg = lane >> 4;
    f32x4 acc[2][1] = {};
    size_t p0 = (size_t)row * 128 + xh * 32;
    int pix = t >> 3, run = t & 7;
    int slot = (run << 5) + (pix ^ run);
    *(uint4*)(smem + slot * 16) = *(const uint4*)(mod_t + (p0 + pix) * 576 + run * 8);
    __syncthreads();
#pragma unroll
    for (int kc = 0; kc < 9; ++kc) {
        char* bb = smem + (kc & 1) * 4096;
        uint4 pre;
        if (kc < 8)
            pre = *(const uint4*)(mod_t + (p0 + pix) * 576 + (kc + 1) * 64 + run * 8);
#pragma unroll
        for (int ks = 0; ks < 2; ++ks) {
            int rn = ks * 4 + kg;
            bf16x8 af[2];
#pragma unroll
            for (int mt = 0; mt < 2; ++mt)
                af[mt] = *(const bf16x8*)(wv_dc2 + (((size_t)kc * 8 + rn) * 64 + wm * 32 + mt * 16 + lm) * 8);
            int n = wn * 16 + lm;
            bf16x8 bf = *(const bf16x8*)(bb + ((rn << 5) + (n ^ rn)) * 16);
#pragma unroll
            for (int mt = 0; mt < 2; ++mt)
                acc[mt][0] = __builtin_amdgcn_mfma_f32_16x16x32_bf16(af[mt], bf, acc[mt][0], 0, 0, 0);
        }
        if (kc < 8) {
            char* nb = smem + ((kc & 1) ^ 1) * 4096;
            *(uint4*)(nb + slot * 16) = pre;
        }
        __syncthreads();
    }
#pragma unroll
    for (int mt = 0; mt < 2; ++mt)
#pragma unroll
        for (int i = 0; i < 4; ++i) {
            int o = wm * 32 + mt * 16 + kg * 4 + i;
            int n = wn * 16 + lm;
            float v = acc[mt][0][i] + bv_dc[o];
            v = v > 0.f ? v : 0.f;
            out[(((size_t)(b * 64 + o)) * 128 + y) * 128 + xh * 32 + n] = v;
        }
}

// ---------------------------------------------------------------------------
// workspace layout: unchanged.
// ---------------------------------------------------------------------------
extern "C" void kernel_launch(void* const* d_in, const int* in_sizes, int n_in,
                              void* d_out, int out_size, void* d_ws, size_t ws_size,
                              hipStream_t stream)
{
    (void)in_sizes; (void)n_in; (void)out_size; (void)ws_size;
    const float* x    = (const float*)d_in[0];
    const float* w_in = (const float*)d_in[1];
    const float* b_in = (const float*)d_in[2];
    const float* w_om = (const float*)d_in[3];
    const float* b_om = (const float*)d_in[4];
    const float* w_dc = (const float*)d_in[5];
    const float* b_dc = (const float*)d_in[6];
    char* ws = (char*)d_ws;
    u16*   x_t    = (u16*)(ws);
    u16*   feat_t = (u16*)(ws + 4326400);
    u16*   feat_c = (u16*)(ws + 8652800);
    u16*   wv_om3 = (u16*)(ws + 12847104);
    u16*   wv_in2 = (u16*)(ws + 15206400);
    u16*   wv_dc2 = (u16*)(ws + 15280128);
    float* bv_om  = (float*)(ws + 15353856);
    float* bv_dc  = (float*)(ws + 15362048);
    u16*   mod_t  = (u16*)(ws + 15362304);

    hipMemsetAsync(ws, 0, 8652800, stream);   // zero x_t + feat_t (conv zero-padding)
    hipLaunchKernelGGL(k_prep, dim3(2432), dim3(256), 0, stream,
                       w_om, b_om, w_in, w_dc, b_dc, x,
                       wv_om3, bv_om, wv_in2, wv_dc2, bv_dc, x_t);
    hipLaunchKernelGGL(k_conv1, dim3(4, 256), dim3(256), 0, stream,
                       wv_in2, b_in, x_t, feat_t, feat_c);
    hipLaunchKernelGGL(k_conv2, dim3(16, 256), dim3(256), 0, stream,
                       wv_om3, bv_om, feat_t, feat_c, mod_t);
    hipLaunchKernelGGL(k_gemm3, dim3(4, 256), dim3(256), 0, stream,
                       wv_dc2, bv_dc, mod_t, (float*)d_out);
}